// Round 11
// baseline (434.410 us; speedup 1.0000x reference)
//
#include <hip/hip_runtime.h>
#include <math.h>

// ---------------------------------------------------------------------------
// FeatureFusionModule, algebraically fused, dtype-adaptive (f32/bf16).
// R16: k3 re-tiled for 2 blocks/CU: wave = (row, px-half, OUT-half) ->
//      acc 4x2 (32 AGPR, was 64), sbuf single [4][130][40] (41.6 KB).
//      ~115 unified regs -> 4 waves/SIMD; two INDEPENDENT blocks per CU
//      interleave at barriers (the 1-block lockstep was the 98us floor).
//      Raw barriers + lgkmcnt only; register prefetch of slab s+1 stays
//      in flight through compute (no vmcnt drain).  bsum back to 64 rps.
//  K0  : detect input dtype (f32 vs bf16) -> flag in ws
//  KWC : convert 19 weight arrays to f32 pool (+WFT) AND pack P16 (merged)
//  K1  : per-image Gram G = X·Yᵀ (MFMA, split-bf16 in f32 mode) + row sums
//  K2a : 64×64 attention math, grid (4,NI): dir x c-half per block
//  K2b : fold attention + conv3x3 + BN into fp16 Wh[n][o][tap][128] + windT
//  K3  : implicit-GEMM conv (MFMA f16) + ReLU + channel stats -> d_out
//  K4  : CBAM channel MLP -> ch scale (256 thr, 64 row-pairs)
//  K5  : per-pixel channel mean/max of fused*ch -> sp_in
//  K6  : 7x7 spatial conv + sigmoid + final scale (in-place on d_out)
// ---------------------------------------------------------------------------

typedef __bf16 bf16_t;
typedef bf16_t bf16x8 __attribute__((ext_vector_type(8)));
typedef bf16_t bf16x4 __attribute__((ext_vector_type(4)));
typedef float  f32x4  __attribute__((ext_vector_type(4)));
typedef _Float16 f16_t;
typedef f16_t  f16x8  __attribute__((ext_vector_type(8)));

static constexpr int  CH  = 64;
static constexpr int  H   = 128;
static constexpr int  W   = 128;
static constexpr int  HW  = H * W;          // 16384
static constexpr int  NI  = 16;             // B*S
static constexpr int  NCK = 16;             // gram chunks per image

// ---- f32 weight pool element offsets ----
static constexpr int W_WQ=0, W_BQ=4096, W_WK=4160, W_BK=8256, W_WV=8320, W_BV=12416,
  W_GAMMA=12480, W_WF=12481, W_BF=86209, W_BNG=86273, W_BNB=86337, W_BNM=86401,
  W_BNV=86465, W_FC1W=86529, W_FC1B=87041, W_FC2W=87049, W_FC2B=87561,
  W_SAW=87625, W_SAB=87723, W_TOTAL=87724;

// ---- workspace layout (bytes) ----
static constexpr size_t OFF_GPART  = 0;
static constexpr size_t SZ_GPART   = (size_t)NI*NCK*4096*4;
static constexpr size_t OFF_SX     = OFF_GPART + SZ_GPART;
static constexpr size_t SZ_SXY     = (size_t)NI*NCK*64*4;
static constexpr size_t OFF_SY     = OFF_SX + SZ_SXY;
static constexpr size_t OFF_M1     = OFF_SY + SZ_SXY;
static constexpr size_t SZ_M       = (size_t)NI*4096*4;
static constexpr size_t OFF_M2     = OFF_M1 + SZ_M;
static constexpr size_t OFF_T1     = OFF_M2 + SZ_M;
static constexpr size_t SZ_T       = (size_t)NI*64*4;
static constexpr size_t OFF_T2     = OFF_T1 + SZ_T;
static constexpr size_t OFF_BCONST = OFF_T2 + SZ_T;
static constexpr size_t OFF_WH     = OFF_BCONST + 256;                  // fp16 weights
static constexpr size_t SZ_WH      = (size_t)NI*64*9*128*2;
static constexpr size_t OFF_WINDT  = OFF_WH + SZ_WH;                    // NI*9*64 f32
static constexpr size_t SZ_WIND    = (size_t)NI*9*64*4;
static constexpr size_t OFF_IND    = OFF_WINDT + SZ_WIND;               // (unused, kept)
static constexpr size_t OFF_BSUM   = OFF_IND + SZ_WIND;
static constexpr size_t SZ_BST     = (size_t)NI*64*64*4;
static constexpr size_t OFF_BMAX   = OFF_BSUM + SZ_BST;
static constexpr size_t OFF_CHS    = OFF_BMAX + SZ_BST;
static constexpr size_t OFF_SPIN   = OFF_CHS + SZ_T;
static constexpr size_t SZ_SPIN    = (size_t)NI*2*HW*4;
static constexpr size_t OFF_FLAG   = OFF_SPIN + SZ_SPIN;
static constexpr size_t OFF_WF32   = OFF_FLAG + 256;
// WFT: transposed fusion weights [tap][8192] f32 (294912 B)
static constexpr size_t OFF_WFT    = ((OFF_WF32 + (size_t)W_TOTAL*4 + 255) / 256) * 256;
static constexpr size_t SZ_WFT     = (size_t)9*8192*4;
// P16: slab-planar f16 inputs, [n][slab4][px16384][ech32], 64 MB (optional)
static constexpr size_t OFF_P16    = ((OFF_WFT + SZ_WFT + 255) / 256) * 256;
static constexpr size_t SZ_P16     = (size_t)NI*4*HW*32*2;

// ===========================================================================
// K0: dtype detection (bf16 N(0,1) never has exponent >= 0xC0 in even u16s)
// ===========================================================================
__global__ __launch_bounds__(256) void k0_detect(
    const unsigned short* __restrict__ u, int* __restrict__ flag)
{
  __shared__ int bad;
  if (threadIdx.x == 0) bad = 0;
  __syncthreads();
  int local = 0;
  for (int i = threadIdx.x; i < 4096; i += 256) {
    const unsigned short v = u[2*i];
    const int e = (v >> 7) & 0xFF;
    if (e >= 0xC0) local = 1;
  }
  if (local) atomicOr(&bad, 1);
  __syncthreads();
  if (threadIdx.x == 0) flag[0] = bad;   // 1 => float32 inputs/outputs
}

// ===========================================================================
// KWC: merged weight-convert (+WFT transpose) and P16 pack.  One launch.
// blocks [0,16384): kc_pack body; blocks [16384, 16384+5472): kw body.
// ===========================================================================
struct WPack { const void* p[19]; int sz[19]; int off[19]; };

__global__ __launch_bounds__(256) void kwc_prep(
    WPack wp, const int* __restrict__ flag, float* __restrict__ dst,
    float* __restrict__ WFT,
    const bf16_t* __restrict__ Xb, const bf16_t* __restrict__ Yb,
    const float* __restrict__ Xf, const float* __restrict__ Yf,
    f16_t* __restrict__ P16, const int useP16)
{
  const int b = blockIdx.x;
  const int f32m = flag[0];
  if (b < 16384) {
    if (!useP16) return;
    const int lin = b * 256 + threadIdx.x;            // [0, 4194304)
    const int oct = lin & 3;
    const int p   = (lin >> 2) & 16383;
    const int s   = (lin >> 16) & 3;
    const int n   = lin >> 18;
    const size_t nbase = (size_t)n * CH * HW;
    const int c0 = (s & 1) * 32 + oct * 8;            // channel within X or Y
    const float*  Fsrc = (s < 2) ? Xf : Yf;
    const bf16_t* Bsrc = (s < 2) ? Xb : Yb;
    f16x8 h;
    #pragma unroll
    for (int j = 0; j < 8; ++j) {
      const size_t q = nbase + (size_t)(c0 + j) * HW + p;
      const float v = f32m ? Fsrc[q] : (float)Bsrc[q];
      h[j] = (f16_t)v;
    }
    *(f16x8*)(P16 + (size_t)lin * 8) = h;
  } else {
    const int bb = b - 16384;                         // 0..5471
    const int j  = bb / 288;                          // 0..18
    const int bx = bb % 288;
    const int i = bx * 256 + threadIdx.x;
    if (i >= wp.sz[j]) return;
    float v;
    if (f32m) v = ((const float*)wp.p[j])[i];
    else      v = (float)((const bf16_t*)wp.p[j])[i];
    dst[wp.off[j] + i] = v;
    if (j == 7) WFT[(i % 9) * 8192 + (i / 9)] = v;    // WF -> [tap][o*128+c]
  }
}

// ===========================================================================
// K1: partial Gram per (n, chunk).  grid (NCK=16, 16 n), block 256 (4 waves)
// f32 mode: split-bf16 (hi+lo), 3 MFMAs; D: row=quad*4+reg, col=lane&15
// ===========================================================================
__global__ __launch_bounds__(256) void k1_gram(
    const bf16_t* __restrict__ Xb, const bf16_t* __restrict__ Yb,
    const float* __restrict__ Xf, const float* __restrict__ Yf,
    const int* __restrict__ flag,
    float* __restrict__ Gpart, float* __restrict__ sxpart, float* __restrict__ sypart)
{
  const int chunk = blockIdx.x, n = blockIdx.y;
  const int t = threadIdx.x, lane = t & 63, wv = t >> 6;
  const int mrow = lane & 15, quad = lane >> 4;
  const int f32m = flag[0];
  const size_t nbase = (size_t)n * CH * HW;
  const int p0 = chunk * 1024 + wv * 256;

  f32x4 acc[4][4], acc2[4][4];
  #pragma unroll
  for (int i = 0; i < 4; ++i)
    #pragma unroll
    for (int j = 0; j < 4; ++j) {
      acc[i][j]  = (f32x4){0.f, 0.f, 0.f, 0.f};
      acc2[i][j] = (f32x4){0.f, 0.f, 0.f, 0.f};
    }
  float sxl[4] = {0.f,0.f,0.f,0.f}, syl[4] = {0.f,0.f,0.f,0.f};

  for (int kt = 0; kt < 8; ++kt) {
    const int pk = p0 + kt * 32 + quad * 8;
    if (f32m) {
      bf16x8 a[4], b[4], al[4], bl[4];
      #pragma unroll
      for (int mt = 0; mt < 4; ++mt) {
        const size_t ia = nbase + (size_t)(mt*16 + mrow) * HW + pk;
        float sa = 0.f, sb = 0.f;
        #pragma unroll
        for (int j = 0; j < 8; ++j) {
          const float va = Xf[ia + j];
          const bf16_t ha = (bf16_t)va;
          a[mt][j] = ha; al[mt][j] = (bf16_t)(va - (float)ha); sa += va;
          const float vb = Yf[ia + j];
          const bf16_t hb = (bf16_t)vb;
          b[mt][j] = hb; bl[mt][j] = (bf16_t)(vb - (float)hb); sb += vb;
        }
        sxl[mt] += sa; syl[mt] += sb;
      }
      #pragma unroll
      for (int mt = 0; mt < 4; ++mt)
        #pragma unroll
        for (int nt = 0; nt < 4; ++nt) {
          acc[mt][nt]  = __builtin_amdgcn_mfma_f32_16x16x32_bf16(a[mt],  b[nt],  acc[mt][nt],  0, 0, 0);
          acc2[mt][nt] = __builtin_amdgcn_mfma_f32_16x16x32_bf16(a[mt],  bl[nt], acc2[mt][nt], 0, 0, 0);
          acc2[mt][nt] = __builtin_amdgcn_mfma_f32_16x16x32_bf16(al[mt], b[nt],  acc2[mt][nt], 0, 0, 0);
        }
    } else {
      bf16x8 a[4], b[4];
      #pragma unroll
      for (int mt = 0; mt < 4; ++mt) {
        const size_t ia = nbase + (size_t)(mt*16 + mrow) * HW + pk;
        a[mt] = *(const bf16x8*)(Xb + ia);
        b[mt] = *(const bf16x8*)(Yb + ia);
        float sa = 0.f, sb = 0.f;
        #pragma unroll
        for (int j = 0; j < 8; ++j) { sa += (float)a[mt][j]; sb += (float)b[mt][j]; }
        sxl[mt] += sa; syl[mt] += sb;
      }
      #pragma unroll
      for (int mt = 0; mt < 4; ++mt)
        #pragma unroll
        for (int nt = 0; nt < 4; ++nt)
          acc[mt][nt] = __builtin_amdgcn_mfma_f32_16x16x32_bf16(a[mt], b[nt], acc[mt][nt], 0, 0, 0);
    }
  }

  #pragma unroll
  for (int mt = 0; mt < 4; ++mt) {
    sxl[mt] += __shfl_xor(sxl[mt], 16, 64); sxl[mt] += __shfl_xor(sxl[mt], 32, 64);
    syl[mt] += __shfl_xor(syl[mt], 16, 64); syl[mt] += __shfl_xor(syl[mt], 32, 64);
  }

  __shared__ float Gs[4096];
  __shared__ float sxs[64], sys[64];
  for (int w2 = 0; w2 < 4; ++w2) {
    if (wv == w2) {
      #pragma unroll
      for (int mt = 0; mt < 4; ++mt) {
        #pragma unroll
        for (int nt = 0; nt < 4; ++nt) {
          #pragma unroll
          for (int r = 0; r < 4; ++r) {
            const int c = mt*16 + quad*4 + r, d = nt*16 + mrow;
            const float val = acc[mt][nt][r] + acc2[mt][nt][r];
            if (w2 == 0) Gs[c*64 + d]  = val;
            else         Gs[c*64 + d] += val;
          }
        }
        if (quad == 0) {
          const int c = mt*16 + mrow;
          if (w2 == 0) { sxs[c] = sxl[mt];  sys[c] = syl[mt]; }
          else         { sxs[c] += sxl[mt]; sys[c] += syl[mt]; }
        }
      }
    }
    __syncthreads();
  }
  float* Gp = Gpart + ((size_t)n*NCK + chunk) * 4096;
  for (int i = t; i < 4096; i += 256) Gp[i] = Gs[i];
  if (t < 64)       sxpart[((size_t)n*NCK + chunk)*64 + t]        = sxs[t];
  else if (t < 128) sypart[((size_t)n*NCK + chunk)*64 + (t - 64)] = sys[t - 64];
}

// ===========================================================================
// K2a: attention small math.  grid (4, NI) -- blockIdx.x = half*2+dir.
// (R12, unchanged)
// ===========================================================================
__global__ __launch_bounds__(256, 1) void k2a_attn(
    const float* __restrict__ Gpart, const float* __restrict__ sxpart, const float* __restrict__ sypart,
    const float* __restrict__ wt,
    float* __restrict__ M1, float* __restrict__ M2,
    float* __restrict__ T1, float* __restrict__ T2)
{
  const int bx = blockIdx.x, n = blockIdx.y;
  const int dir  = bx & 1;          // 0: s1 path, 1: s2 path
  const int c0   = (bx >> 1) * 32;  // c-half base
  const int t = threadIdx.x;
  constexpr int SW = 68;            // 272 B rows: 16B-aligned for all rows
  __shared__ float Gs[4096];
  __shared__ float Ps[4096];        // P rows (own c half used)
  __shared__ float As[64*SW];       // A rows (own c half used)
  __shared__ float WQs[64*SW], WKs[64*SW], WVs[64*SW];
  __shared__ float sxs[64], sys[64], uu[64], vv[64];

  for (int i = t; i < 4096; i += 256) {
    const int r = i >> 6, cc = i & 63;
    WQs[r*SW + cc] = wt[W_WQ + i];
    WKs[r*SW + cc] = wt[W_WK + i];
    WVs[r*SW + cc] = wt[W_WV + i];
  }
  for (int i4 = t; i4 < 1024; i4 += 256) {
    f32x4 s = (f32x4){0.f, 0.f, 0.f, 0.f};
    for (int c2 = 0; c2 < NCK; ++c2)
      s += *(const f32x4*)(Gpart + ((size_t)n*NCK + c2)*4096 + i4*4);
    *(f32x4*)(Gs + i4*4) = s;
  }
  if (t < 64) {
    float s = 0.f; for (int c2 = 0; c2 < NCK; ++c2) s += sxpart[((size_t)n*NCK + c2)*64 + t];
    sxs[t] = s;
  } else if (t < 128) {
    const int c = t - 64;
    float s = 0.f; for (int c2 = 0; c2 < NCK; ++c2) s += sypart[((size_t)n*NCK + c2)*64 + c];
    sys[c] = s;
  }
  __syncthreads();

  // ---- phase 2: P = WQ·G (dir0) or WQ·Gᵀ (dir1), own c rows ----
  {
    const int e = t & 63;
    float Greg[64];
    if (dir == 0) {
      #pragma unroll
      for (int a = 0; a < 64; ++a) Greg[a] = Gs[a*64 + e];     // col e
    } else {
      #pragma unroll
      for (int a4 = 0; a4 < 16; ++a4)                          // row e
        *(f32x4*)(Greg + a4*4) = *(const f32x4*)(Gs + e*64 + a4*4);
    }
    for (int it = 0; it < 8; ++it) {
      const int c = c0 + (t >> 6) + 4*it;                      // wave-uniform
      float s1 = 0.f;
      #pragma unroll
      for (int a4 = 0; a4 < 16; ++a4) {
        const f32x4 w4 = *(const f32x4*)(WQs + c*SW + a4*4);   // uniform b128
        #pragma unroll
        for (int r = 0; r < 4; ++r) s1 += w4[r] * Greg[a4*4 + r];
      }
      Ps[c*64 + e] = s1;
    }
  }
  // ---- uu[all c], vv[all d] ----
  {
    const int c = t & 63;
    if (t < 64) {
      const float* vecv = dir ? sys : sxs;
      float s = 0.f;
      #pragma unroll
      for (int a = 0; a < 64; ++a) s += WQs[c*SW + a] * vecv[a];
      uu[c] = s;
    } else if (t < 128) {
      const float* vecv = dir ? sxs : sys;
      float s = 0.f;
      #pragma unroll
      for (int a = 0; a < 64; ++a) s += WKs[c*SW + a] * vecv[a];
      vv[c] = s;
    }
  }
  __syncthreads();

  // ---- phase 3: A = P·WKᵀ + bias, own c rows ----
  {
    const int d = t & 63;
    float WKreg[64];
    #pragma unroll
    for (int a4 = 0; a4 < 16; ++a4)
      *(f32x4*)(WKreg + a4*4) = *(const f32x4*)(WKs + d*SW + a4*4);
    const float bkd = wt[W_BK + d];
    for (int it = 0; it < 8; ++it) {
      const int c = c0 + (t >> 6) + 4*it;
      float s1 = 0.f;
      #pragma unroll
      for (int e4 = 0; e4 < 16; ++e4) {
        const f32x4 p1 = *(const f32x4*)(Ps + c*64 + e4*4);    // uniform b128
        #pragma unroll
        for (int r = 0; r < 4; ++r) s1 += p1[r] * WKreg[e4*4 + r];
      }
      const float bqc = wt[W_BQ + c];
      s1 += uu[c]*bkd + bqc*vv[d] + 16384.f*bqc*bkd;
      As[c*SW + d] = s1;
    }
  }
  __syncthreads();

  // ---- softmax rows (own 32 rows) ----
  if (t < 32) {
    float* R = As + (c0 + t)*SW;
    float m = R[0];
    for (int d = 1; d < 64; ++d) m = fmaxf(m, R[d]);
    float s = 0.f;
    for (int d = 0; d < 64; ++d) { const float e2 = expf(R[d] - m); R[d] = e2; s += e2; }
    const float inv = 1.f / s;
    for (int d = 0; d < 64; ++d) R[d] *= inv;
  }
  __syncthreads();

  // ---- phase 5: M = A·WV, own c rows (+T tail) ----
  {
    const int e = t & 63;
    float WVreg[64];
    #pragma unroll
    for (int dd = 0; dd < 64; ++dd) WVreg[dd] = WVs[dd*SW + e];
    float* Mo = (dir ? M2 : M1) + (size_t)n*4096;
    for (int it = 0; it < 8; ++it) {
      const int c = c0 + (t >> 6) + 4*it;
      float s1 = 0.f;
      #pragma unroll
      for (int d4 = 0; d4 < 16; ++d4) {
        const f32x4 a1 = *(const f32x4*)(As + c*SW + d4*4);    // uniform b128
        #pragma unroll
        for (int r = 0; r < 4; ++r) s1 += a1[r] * WVreg[d4*4 + r];
      }
      Mo[c*64 + e] = s1;
    }
  }
  if (t < 32) {
    const int c = c0 + t;
    float s1 = 0.f;
    for (int d = 0; d < 64; ++d) s1 += As[c*SW + d] * wt[W_BV + d];
    (dir ? T2 : T1)[n*64 + c] = s1;
  }
}

// ===========================================================================
// K2b: effective conv weights -> fp16 Wh[n][o][tap][128] (+windT, bconst).
// grid (9 taps, 2 dirs, 16 n), block 256.  (R10, unchanged)
// ===========================================================================
__global__ __launch_bounds__(256) void k2b_weff(
    const float* __restrict__ wt, const float* __restrict__ WFT,
    const float* __restrict__ M1, const float* __restrict__ M2,
    const float* __restrict__ T1, const float* __restrict__ T2,
    f16_t* __restrict__ Wh, float* __restrict__ windT, float* __restrict__ bconst)
{
  const int tap = blockIdx.x, dir = blockIdx.y, n = blockIdx.z;
  const int t = threadIdx.x;
  const float g = wt[W_GAMMA];
  f16_t* Whn = Wh + (size_t)n * 64 * 9 * 128;
  const float* Mo = (dir == 0) ? (M2 + (size_t)n*4096) : (M1 + (size_t)n*4096);

  __shared__ float Wfs[8192];   // [o][0..127] WF row slice at this tap
  __shared__ float Ms[4096];    // Mo[c][e]

  for (int i4 = t; i4 < 2048; i4 += 256)
    *(f32x4*)(Wfs + i4*4) = *(const f32x4*)(WFT + (size_t)tap*8192 + i4*4);
  for (int i4 = t; i4 < 1024; i4 += 256)
    *(f32x4*)(Ms + i4*4) = *(const f32x4*)(Mo + i4*4);
  __syncthreads();

  const int e = t & 63;
  float Msreg[64];
  #pragma unroll
  for (int c = 0; c < 64; ++c) Msreg[c] = Ms[c*64 + e];
  const int coff = dir ? 0 : 64;        // inner-sum weight half
  const int boff = dir ? 64 : 0;        // base half
  for (int it = 0; it < 16; ++it) {
    const int o = (t >> 6) + 4*it;      // wave-uniform
    const float inv = wt[W_BNG + o] * rsqrtf(wt[W_BNV + o] + 1e-5f);
    const float base = Wfs[o*128 + boff + e];
    float s = 0.f;
    #pragma unroll
    for (int c4 = 0; c4 < 16; ++c4) {
      const f32x4 w4 = *(const f32x4*)(Wfs + o*128 + coff + c4*4);
      #pragma unroll
      for (int r = 0; r < 4; ++r) s += w4[r] * Msreg[c4*4 + r];
    }
    Whn[(o*9 + tap)*128 + dir*64 + e] = (f16_t)(inv * (base + g * s));
  }

  if (dir == 0 && t < 64) {
    const int o = t;
    const float inv = wt[W_BNG + o] * rsqrtf(wt[W_BNV + o] + 1e-5f);
    float s = 0.f;
    for (int c = 0; c < 64; ++c)
      s += wt[W_WF + (o*128 + c)*9 + tap]      * T1[n*64 + c]
         + wt[W_WF + (o*128 + 64 + c)*9 + tap] * T2[n*64 + c];
    windT[((size_t)n*9 + tap)*64 + o] = inv * g * s;
    if (tap == 0 && n == 0)
      bconst[o] = wt[W_BF + o]*inv + wt[W_BNB + o] - wt[W_BNM + o]*inv;
  }
}

// ===========================================================================
// K3: implicit-GEMM conv via MFMA f16.
// R16: grid (64 row-pairs, 16 n), block 512 (8 waves).
// Wave wv: ly=wv>>2 (row 0/1), ch2=(wv>>1)&1 (px half), oh=wv&1 (out half).
// Each wave: 64 px x 32 out, acc 4x2 (32 AGPR).  sbuf[4][130][40] single
// buffer (41.6 KB) -> 2 blocks/CU co-resident; their barriers interleave.
// Raw barriers + lgkmcnt only; slab s+1 global loads issued before compute
// of slab s (vmcnt never drained at barriers).
// ===========================================================================
__global__ __launch_bounds__(512) void k3_conv(
    const bf16_t* __restrict__ Xb, const bf16_t* __restrict__ Yb,
    const float* __restrict__ Xf, const float* __restrict__ Yf,
    const int* __restrict__ flag,
    const f16_t* __restrict__ Wh, const float* __restrict__ bconst,
    const float* __restrict__ windT,
    const f16_t* __restrict__ P16, const int useP16,
    bf16_t* __restrict__ fusedB, float* __restrict__ fusedF,
    float* __restrict__ bsum, float* __restrict__ bmax)
{
  __shared__ __attribute__((aligned(16))) f16_t sbuf[4][130][40];
  __shared__ float sind[576], sconst[64];
  __shared__ float ssum[8][64], smax[8][64];
  const int rp = blockIdx.x, n = blockIdx.y;        // rp: 0..63 (2 rows each)
  const int t = threadIdx.x, lane = t & 63, wv = t >> 6;
  const int l15 = lane & 15, quad = lane >> 4;
  const int ly = wv >> 2, ch2 = (wv >> 1) & 1, oh = wv & 1;
  const int f32m = flag[0];
  const size_t nbase = (size_t)n * CH * HW;
  const f16_t* __restrict__ Whn = Wh + (size_t)n * 64 * 9 * 128;

  // border table from windT (k2c folded in)
  for (int i = t; i < 576; i += 512) {
    const int g = i >> 6, o = i & 63;
    const int yc = g / 3, xc = g % 3;
    const int ky0 = (yc == 0) ? 1 : 0, ky1 = (yc == 2) ? 1 : 2;
    const int kx0 = (xc == 0) ? 1 : 0, kx1 = (xc == 2) ? 1 : 2;
    float sv = 0.f;
    for (int ky = ky0; ky <= ky1; ++ky)
      for (int kx = kx0; kx <= kx1; ++kx)
        sv += windT[((size_t)n*9 + ky*3 + kx)*64 + o];
    sind[i] = sv;
  }
  if (t < 64) sconst[t] = bconst[t];
  if (t < 256) { // zero halo columns once (4 rows x 2 cols x 32 slots)
    const int r = t >> 6, cs = (t >> 5) & 1, sl = t & 31;
    sbuf[r][cs ? 129 : 0][sl] = (f16_t)0.f;
  }

  f32x4 acc[4][2];
  #pragma unroll
  for (int i = 0; i < 4; ++i)
    #pragma unroll
    for (int j = 0; j < 2; ++j) acc[i][j] = (f32x4){0.f, 0.f, 0.f, 0.f};

  if (useP16) {
    const int oct = t & 3;
    const int x   = t >> 2;                 // 0..127
    const f16_t* __restrict__ PnB = P16 + (size_t)(n*4) * HW * 32;
    f16x8 h[4];

    #define K3_STAGE_LOAD(S)                                                  \
      { const f16_t* __restrict__ Pn = PnB + (size_t)(S) * HW * 32;           \
        _Pragma("unroll")                                                     \
        for (int i = 0; i < 4; ++i) {                                         \
          const int gy = rp*2 - 1 + i;                                        \
          f16x8 v;                                                            \
          _Pragma("unroll")                                                   \
          for (int k2 = 0; k2 < 8; ++k2) v[k2] = (f16_t)0.f;                  \
          if (gy >= 0 && gy < H)                                              \
            v = *(const f16x8*)(Pn + ((size_t)(gy*128 + x) * 32 + oct*8));    \
          h[i] = v;                                                           \
        } }
    #define K3_STAGE_WRITE()                                                  \
      { const int colL = x + 1;                                               \
        _Pragma("unroll")                                                     \
        for (int i = 0; i < 4; ++i)                                           \
          *(f16x8*)&sbuf[i][colL][(oct ^ (colL & 3)) * 8] = h[i];             \
      }

    K3_STAGE_LOAD(0)
    for (int s = 0; s < 4; ++s) {
      __builtin_amdgcn_s_barrier();         // prev slab's reads complete
      K3_STAGE_WRITE()                      // (compiler waits vmcnt for h)
      asm volatile("s_waitcnt lgkmcnt(0)" ::: "memory");
      __builtin_amdgcn_s_barrier();         // writes visible to all waves
      if (s < 3) K3_STAGE_LOAD(s + 1)       // in flight through compute
      __builtin_amdgcn_s_setprio(1);
      #pragma unroll
      for (int tap = 0; tap < 9; ++tap) {
        const int ky = tap / 3, kx = tap % 3;
        f16x8 bfr[2];
        #pragma unroll
        for (int nt = 0; nt < 2; ++nt) {
          const int o = oh*32 + nt*16 + l15;
          bfr[nt] = *(const f16x8*)(Whn + ((o*9 + tap)*128 + s*32 + quad*8));
        }
        f16x8 afr[4];
        const int row = ly + ky;
        #pragma unroll
        for (int mt = 0; mt < 4; ++mt) {
          const int col = ch2*64 + mt*16 + l15 + kx;
          afr[mt] = *(const f16x8*)&sbuf[row][col][(quad ^ (col & 3)) * 8];
        }
        #pragma unroll
        for (int mt = 0; mt < 4; ++mt)
          #pragma unroll
          for (int nt = 0; nt < 2; ++nt)
            acc[mt][nt] = __builtin_amdgcn_mfma_f32_16x16x32_f16(afr[mt], bfr[nt], acc[mt][nt], 0, 0, 0);
      }
      __builtin_amdgcn_s_setprio(0);
    }
    #undef K3_STAGE_LOAD
    #undef K3_STAGE_WRITE
  } else {
    // fallback: classic staged loop, direct global loads + converts
    const int cstage = t & 127, rsel = t >> 7;          // rsel 0..3
    for (int s = 0; s < 4; ++s) {
      __syncthreads();
      {
        const int r = rsel;
        const int gy = rp*2 - 1 + r;
        const bool valid = (gy >= 0) && (gy < H);
        const int colL = cstage + 1;
        #pragma unroll
        for (int oct = 0; oct < 4; ++oct) {
          f16x8 hh;
          #pragma unroll
          for (int j = 0; j < 8; ++j) {
            const int g = s*32 + oct*8 + j;
            float v = 0.f;
            if (valid) {
              const size_t q = nbase + (size_t)(g & 63)*HW + gy*W + cstage;
              v = (g < 64) ? (f32m ? Xf[q] : (float)Xb[q])
                           : (f32m ? Yf[q] : (float)Yb[q]);
            }
            hh[j] = (f16_t)v;
          }
          *(f16x8*)&sbuf[r][colL][(oct ^ (colL & 3)) * 8] = hh;
        }
      }
      __syncthreads();
      #pragma unroll
      for (int tap = 0; tap < 9; ++tap) {
        const int ky = tap / 3, kx = tap % 3;
        f16x8 bfr[2];
        #pragma unroll
        for (int nt = 0; nt < 2; ++nt) {
          const int o = oh*32 + nt*16 + l15;
          bfr[nt] = *(const f16x8*)(Whn + ((o*9 + tap)*128 + s*32 + quad*8));
        }
        f16x8 afr[4];
        const int row = ly + ky;
        #pragma unroll
        for (int mt = 0; mt < 4; ++mt) {
          const int col = ch2*64 + mt*16 + l15 + kx;
          afr[mt] = *(const f16x8*)&sbuf[row][col][(quad ^ (col & 3)) * 8];
        }
        #pragma unroll
        for (int mt = 0; mt < 4; ++mt)
          #pragma unroll
          for (int nt = 0; nt < 2; ++nt)
            acc[mt][nt] = __builtin_amdgcn_mfma_f32_16x16x32_f16(afr[mt], bfr[nt], acc[mt][nt], 0, 0, 0);
      }
    }
  }

  // ---- epilogue: + bconst + border const, ReLU, store, channel stats ----
  const int y = rp*2 + ly;
  const int yc = (y == 0) ? 0 : (y == H-1) ? 2 : 1;
  #pragma unroll
  for (int nt = 0; nt < 2; ++nt) {
    const int o = oh*32 + nt*16 + l15;
    const float bc = sconst[o];
    float ssm = 0.f, smx = 0.f;
    #pragma unroll
    for (int mt = 0; mt < 4; ++mt) {
      const int xb = ch2*64 + mt*16 + quad*4;
      f32x4 vals;
      #pragma unroll
      for (int r = 0; r < 4; ++r) {
        const int x = xb + r;
        const int xc = (x == 0) ? 0 : (x == W-1) ? 2 : 1;
        float v = acc[mt][nt][r] + bc + sind[(yc*3 + xc)*64 + o];
        v = fmaxf(v, 0.f);
        vals[r] = v; ssm += v; smx = fmaxf(smx, v);
      }
      const size_t off = nbase + (size_t)o*HW + y*W + xb;
      if (f32m) {
        *(f32x4*)(fusedF + off) = vals;
      } else {
        bf16x4 pv;
        #pragma unroll
        for (int r = 0; r < 4; ++r) pv[r] = (bf16_t)vals[r];
        *(bf16x4*)(fusedB + off) = pv;
      }
    }
    ssm += __shfl_xor(ssm, 16, 64); ssm += __shfl_xor(ssm, 32, 64);
    smx = fmaxf(smx, __shfl_xor(smx, 16, 64));
    smx = fmaxf(smx, __shfl_xor(smx, 32, 64));
    if (quad == 0) { ssum[wv][o] = ssm; smax[wv][o] = smx; }
  }
  __syncthreads();
  if (t < 64) {
    const int base = (t >= 32) ? 1 : 0;   // waves with oh matching this o
    float S = 0.f, M = 0.f;
    #pragma unroll
    for (int k = 0; k < 4; ++k) {
      S += ssum[base + 2*k][t];
      M = fmaxf(M, smax[base + 2*k][t]);
    }
    bsum[((size_t)n*64 + rp)*64 + t] = S;
    bmax[((size_t)n*64 + rp)*64 + t] = M;
  }
}

// ===========================================================================
// K4: CBAM channel gate.  grid 16 (per n), block 256 (4-way rp split, 64 rps)
// ===========================================================================
__global__ __launch_bounds__(256) void k4_chgate(
    const float* __restrict__ bsum, const float* __restrict__ bmax,
    const float* __restrict__ wt, float* __restrict__ chout)
{
  const int n = blockIdx.x, t = threadIdx.x;
  const int o = t & 63, part = t >> 6;
  __shared__ float ps[4][64], pm[4][64];
  __shared__ float avg[64], mxs[64], h1[8], h2[8];
  float S = 0.f, M = 0.f;
  for (int rp = part*16; rp < part*16 + 16; ++rp) {
    S += bsum[((size_t)n*64 + rp)*64 + o];
    M = fmaxf(M, bmax[((size_t)n*64 + rp)*64 + o]);
  }
  ps[part][o] = S; pm[part][o] = M;
  __syncthreads();
  if (t < 64) {
    const float Sa = ((ps[0][t] + ps[1][t]) + ps[2][t]) + ps[3][t];
    const float Ma = fmaxf(fmaxf(pm[0][t], pm[1][t]), fmaxf(pm[2][t], pm[3][t]));
    avg[t] = Sa * (1.f / 16384.f);
    mxs[t] = Ma;
  }
  __syncthreads();
  if (t < 8) {
    float s = wt[W_FC1B + t];
    for (int c = 0; c < 64; ++c) s += wt[W_FC1W + t*64 + c] * avg[c];
    h1[t] = fmaxf(s, 0.f);
  } else if (t < 16) {
    const int r = t - 8;
    float s = wt[W_FC1B + r];
    for (int c = 0; c < 64; ++c) s += wt[W_FC1W + r*64 + c] * mxs[c];
    h2[r] = fmaxf(s, 0.f);
  }
  __syncthreads();
  if (t < 64) {
    float s = 2.f * wt[W_FC2B + t];
    for (int r = 0; r < 8; ++r) s += wt[W_FC2W + t*8 + r] * (h1[r] + h2[r]);
    chout[n*64 + t] = 1.f / (1.f + expf(-s));
  }
}

// ===========================================================================
// K5: spatial-attention inputs (per-pixel channel mean/max of fused*ch).
// grid (32, NI), block 256 (4 waves).  (R14, unchanged)
// ===========================================================================
__global__ __launch_bounds__(256) void k5_spin(
    const bf16_t* __restrict__ fusedB, const float* __restrict__ fusedF,
    const int* __restrict__ flag,
    const float* __restrict__ chs, float* __restrict__ spin)
{
  const int n = blockIdx.y;
  const int t = threadIdx.x, w = t >> 6, lane = t & 63;
  const int px0 = blockIdx.x * 512 + lane * 8;
  const int f32m = flag[0];
  const size_t nbase = (size_t)n * CH * HW;
  const float* c = chs + n * 64;
  __shared__ float Ssum[4][64][9], Smax[4][64][9];   // pad 9: conflict-free
  float s[8], m[8];
  #pragma unroll
  for (int k = 0; k < 8; ++k) { s[k] = 0.f; m[k] = 0.f; }
  const int o0 = w * 16;
  if (f32m) {
    for (int oi = 0; oi < 16; ++oi) {
      const int o = o0 + oi;
      const float co = c[o];
      const float* q = fusedF + nbase + (size_t)o*HW + px0;
      const f32x4 a = *(const f32x4*)q;
      const f32x4 b = *(const f32x4*)(q + 4);
      #pragma unroll
      for (int k = 0; k < 4; ++k) {
        const float v0 = a[k] * co; s[k]   += v0; m[k]   = fmaxf(m[k],   v0);
        const float v1 = b[k] * co; s[4+k] += v1; m[4+k] = fmaxf(m[4+k], v1);
      }
    }
  } else {
    for (int oi = 0; oi < 16; ++oi) {
      const int o = o0 + oi;
      const float co = c[o];
      const bf16x8 a = *(const bf16x8*)(fusedB + nbase + (size_t)o*HW + px0);
      #pragma unroll
      for (int k = 0; k < 8; ++k) {
        const float v = (float)a[k] * co; s[k] += v; m[k] = fmaxf(m[k], v);
      }
    }
  }
  #pragma unroll
  for (int k = 0; k < 8; ++k) { Ssum[w][lane][k] = s[k]; Smax[w][lane][k] = m[k]; }
  __syncthreads();
  if (t < 64) {
    const int p0 = blockIdx.x * 512 + t * 8;
    f32x4 o0v, o1v, o2v, o3v;
    #pragma unroll
    for (int k = 0; k < 8; ++k) {
      const float S = ((Ssum[0][t][k] + Ssum[1][t][k]) + Ssum[2][t][k]) + Ssum[3][t][k];
      const float M = fmaxf(fmaxf(Smax[0][t][k], Smax[1][t][k]),
                            fmaxf(Smax[2][t][k], Smax[3][t][k]));
      if (k < 4) { o0v[k] = S * (1.f/64.f); o2v[k] = M; }
      else       { o1v[k-4] = S * (1.f/64.f); o3v[k-4] = M; }
    }
    *(f32x4*)(spin + (size_t)n*2*HW + p0)          = o0v;
    *(f32x4*)(spin + (size_t)n*2*HW + p0 + 4)      = o1v;
    *(f32x4*)(spin + (size_t)n*2*HW + HW + p0)     = o2v;
    *(f32x4*)(spin + (size_t)n*2*HW + HW + p0 + 4) = o3v;
  }
}

// ===========================================================================
// K6: 7x7 spatial conv + sigmoid + final scale (in-place on d_out).
// grid (32, NI), block 256.  (R14, unchanged)
// ===========================================================================
__global__ __launch_bounds__(256) void k6_final(
    bf16_t* __restrict__ fusedB, float* __restrict__ fusedF,
    const int* __restrict__ flag,
    const float* __restrict__ chs, const float* __restrict__ spin,
    const float* __restrict__ wt)
{
  const int n = blockIdx.y;
  const int t = threadIdx.x;
  const int y0 = blockIdx.x * 4;
  const int f32m = flag[0];
  const float* s0 = spin + (size_t)n*2*HW;
  const float* s1 = s0 + HW;
  __shared__ float s0l[10][128], s1l[10][128];
  __shared__ float spl[8][64];                 // [pxk][pxgroup] transposed

  for (int i = t; i < 1280; i += 256) {
    const int r = i >> 7, x = i & 127;
    const int yy = y0 - 3 + r;
    const bool ok = (yy >= 0) && (yy < H);
    s0l[r][x] = ok ? s0[yy*W + x] : 0.f;
    s1l[r][x] = ok ? s1[yy*W + x] : 0.f;
  }
  __syncthreads();

  #pragma unroll
  for (int pp = 0; pp < 2; ++pp) {
    const int pl = t*2 + pp;                   // 0..511
    const int ly = pl >> 7, x = pl & 127;
    float acc = wt[W_SAB];
    #pragma unroll
    for (int j = 0; j < 7; ++j) {
      const int row = ly + j;                  // LDS row for yy = y0+ly+j-3
      #pragma unroll
      for (int i = 0; i < 7; ++i) {
        const int xx = x + i - 3;
        const bool ok = (xx >= 0) && (xx < W);
        const float v0 = ok ? s0l[row][xx] : 0.f;
        const float v1 = ok ? s1l[row][xx] : 0.f;
        acc += wt[W_SAW + j*7 + i] * v0 + wt[W_SAW + 49 + j*7 + i] * v1;
      }
    }
    spl[pl & 7][pl >> 3] = 1.f / (1.f + expf(-acc));
  }
  __syncthreads();

  const size_t nbase = (size_t)n * CH * HW;
  const float* c = chs + n * 64;
  const int g = t & 63;                        // px group (8 px)
  const int p0 = y0*W + g*8;
  float sp[8];
  #pragma unroll
  for (int k = 0; k < 8; ++k) sp[k] = spl[k][g];
  for (int it = 0; it < 16; ++it) {
    const int o = it*4 + (t >> 6);             // wave-uniform channel
    const float co = c[o];
    if (f32m) {
      float* q = fusedF + nbase + (size_t)o*HW + p0;
      f32x4 a = *(f32x4*)q;
      f32x4 b = *(f32x4*)(q + 4);
      #pragma unroll
      for (int k = 0; k < 4; ++k) {
        a[k] = a[k] * co * sp[k];
        b[k] = b[k] * co * sp[4+k];
      }
      *(f32x4*)q       = a;
      *(f32x4*)(q + 4) = b;
    } else {
      bf16_t* q = fusedB + nbase + (size_t)o*HW + p0;
      bf16x8 a = *(bf16x8*)q;
      #pragma unroll
      for (int k = 0; k < 8; ++k)
        a[k] = (bf16_t)((float)a[k] * co * sp[k]);
      *(bf16x8*)q = a;
    }
  }
}

// ===========================================================================
extern "C" void kernel_launch(void* const* d_in, const int* in_sizes, int n_in,
                              void* d_out, int out_size, void* d_ws, size_t ws_size,
                              hipStream_t stream)
{
  (void)n_in; (void)out_size; (void)in_sizes;
  char* ws = (char*)d_ws;
  float*  Gpart  = (float*)(ws + OFF_GPART);
  float*  sxp    = (float*)(ws + OFF_SX);
  float*  syp    = (float*)(ws + OFF_SY);
  float*  M1     = (float*)(ws + OFF_M1);
  float*  M2     = (float*)(ws + OFF_M2);
  float*  T1     = (float*)(ws + OFF_T1);
  float*  T2     = (float*)(ws + OFF_T2);
  float*  bconst = (float*)(ws + OFF_BCONST);
  f16_t*  Wh     = (f16_t*)(ws + OFF_WH);
  float*  windT  = (float*)(ws + OFF_WINDT);
  float*  bsum   = (float*)(ws + OFF_BSUM);
  float*  bmax   = (float*)(ws + OFF_BMAX);
  float*  chs    = (float*)(ws + OFF_CHS);
  float*  spin   = (float*)(ws + OFF_SPIN);
  int*    flag   = (int*)  (ws + OFF_FLAG);
  float*  wf32   = (float*)(ws + OFF_WF32);
  float*  wft    = (float*)(ws + OFF_WFT);
  f16_t*  P16    = (f16_t*)(ws + OFF_P16);
  bf16_t* fusedB = (bf16_t*)d_out;
  float*  fusedF = (float*)d_out;

  const int useP16 = (ws_size >= OFF_P16 + SZ_P16) ? 1 : 0;

  const bf16_t* imgB = (const bf16_t*)d_in[0];
  const bf16_t* depB = (const bf16_t*)d_in[1];
  const float*  imgF = (const float*) d_in[0];
  const float*  depF = (const float*) d_in[1];

  WPack wp;
  static const int wsz[19] = {4096,64,4096,64,4096,64,1,73728,64,64,64,64,64,512,8,512,64,98,1};
  static const int woff[19] = {W_WQ,W_BQ,W_WK,W_BK,W_WV,W_BV,W_GAMMA,W_WF,W_BF,W_BNG,
                               W_BNB,W_BNM,W_BNV,W_FC1W,W_FC1B,W_FC2W,W_FC2B,W_SAW,W_SAB};
  for (int j = 0; j < 19; ++j) { wp.p[j] = d_in[2 + j]; wp.sz[j] = wsz[j]; wp.off[j] = woff[j]; }

  hipLaunchKernelGGL(k0_detect, dim3(1), dim3(256), 0, stream,
                     (const unsigned short*)d_in[0], flag);
  hipLaunchKernelGGL(kwc_prep, dim3(16384 + 5472), dim3(256), 0, stream,
                     wp, flag, wf32, wft, imgB, depB, imgF, depF, P16, useP16);
  hipLaunchKernelGGL(k1_gram,  dim3(NCK, NI), dim3(256), 0, stream,
                     imgB, depB, imgF, depF, flag, Gpart, sxp, syp);
  hipLaunchKernelGGL(k2a_attn, dim3(4, NI), dim3(256), 0, stream,
                     Gpart, sxp, syp, wf32, M1, M2, T1, T2);
  hipLaunchKernelGGL(k2b_weff, dim3(9, 2, NI), dim3(256), 0, stream,
                     wf32, wft, M1, M2, T1, T2, Wh, windT, bconst);
  hipLaunchKernelGGL(k3_conv,  dim3(64, NI), dim3(512), 0, stream,
                     imgB, depB, imgF, depF, flag, Wh, bconst, windT,
                     P16, useP16, fusedB, fusedF, bsum, bmax);
  hipLaunchKernelGGL(k4_chgate, dim3(NI), dim3(256), 0, stream,
                     bsum, bmax, wf32, chs);
  hipLaunchKernelGGL(k5_spin,  dim3(32, NI), dim3(256), 0, stream,
                     fusedB, fusedF, flag, chs, spin);
  hipLaunchKernelGGL(k6_final, dim3(32, NI), dim3(256), 0, stream,
                     fusedB, fusedF, flag, chs, spin, wf32);
}

// Round 12
// 412.328 us; speedup vs baseline: 1.0536x; 1.0536x over previous
//
#include <hip/hip_runtime.h>
#include <math.h>

// ---------------------------------------------------------------------------
// FeatureFusionModule, algebraically fused, dtype-adaptive (f32/bf16).
// R17: revert to R15 (measured best, 414 us).  R16's smaller k3 tiles
//      regressed (halo overfetch returned, bank conflicts doubled, no
//      second co-resident block materialized).  k3 kept at its R15 form:
//      double-buffered LDS, one barrier per slab, register prefetch.
//  K0  : detect input dtype (f32 vs bf16) -> flag in ws
//  KWC : convert 19 weight arrays to f32 pool (+WFT) AND pack P16 (merged)
//  K1  : per-image Gram G = X·Yᵀ (MFMA, split-bf16 in f32 mode) + row sums
//  K2a : 64×64 attention math, grid (4,NI): dir x c-half per block
//  K2b : fold attention + conv3x3 + BN into fp16 Wh[n][o][tap][128] + windT
//  K3  : implicit-GEMM conv (MFMA f16) + ReLU + channel stats -> d_out
//  K4  : CBAM channel MLP -> ch scale (256 thr, 32 row-quads)
//  K5  : per-pixel channel mean/max of fused*ch -> sp_in
//  K6  : 7x7 spatial conv + sigmoid + final scale (in-place on d_out)
// ---------------------------------------------------------------------------

typedef __bf16 bf16_t;
typedef bf16_t bf16x8 __attribute__((ext_vector_type(8)));
typedef bf16_t bf16x4 __attribute__((ext_vector_type(4)));
typedef float  f32x4  __attribute__((ext_vector_type(4)));
typedef _Float16 f16_t;
typedef f16_t  f16x8  __attribute__((ext_vector_type(8)));

static constexpr int  CH  = 64;
static constexpr int  H   = 128;
static constexpr int  W   = 128;
static constexpr int  HW  = H * W;          // 16384
static constexpr int  NI  = 16;             // B*S
static constexpr int  NCK = 16;             // gram chunks per image

// ---- f32 weight pool element offsets ----
static constexpr int W_WQ=0, W_BQ=4096, W_WK=4160, W_BK=8256, W_WV=8320, W_BV=12416,
  W_GAMMA=12480, W_WF=12481, W_BF=86209, W_BNG=86273, W_BNB=86337, W_BNM=86401,
  W_BNV=86465, W_FC1W=86529, W_FC1B=87041, W_FC2W=87049, W_FC2B=87561,
  W_SAW=87625, W_SAB=87723, W_TOTAL=87724;

// ---- workspace layout (bytes) ----
static constexpr size_t OFF_GPART  = 0;
static constexpr size_t SZ_GPART   = (size_t)NI*NCK*4096*4;
static constexpr size_t OFF_SX     = OFF_GPART + SZ_GPART;
static constexpr size_t SZ_SXY     = (size_t)NI*NCK*64*4;
static constexpr size_t OFF_SY     = OFF_SX + SZ_SXY;
static constexpr size_t OFF_M1     = OFF_SY + SZ_SXY;
static constexpr size_t SZ_M       = (size_t)NI*4096*4;
static constexpr size_t OFF_M2     = OFF_M1 + SZ_M;
static constexpr size_t OFF_T1     = OFF_M2 + SZ_M;
static constexpr size_t SZ_T       = (size_t)NI*64*4;
static constexpr size_t OFF_T2     = OFF_T1 + SZ_T;
static constexpr size_t OFF_BCONST = OFF_T2 + SZ_T;
static constexpr size_t OFF_WH     = OFF_BCONST + 256;                  // fp16 weights
static constexpr size_t SZ_WH      = (size_t)NI*64*9*128*2;
static constexpr size_t OFF_WINDT  = OFF_WH + SZ_WH;                    // NI*9*64 f32
static constexpr size_t SZ_WIND    = (size_t)NI*9*64*4;
static constexpr size_t OFF_IND    = OFF_WINDT + SZ_WIND;               // (unused, kept)
static constexpr size_t OFF_BSUM   = OFF_IND + SZ_WIND;
static constexpr size_t SZ_BST     = (size_t)NI*64*64*4;
static constexpr size_t OFF_BMAX   = OFF_BSUM + SZ_BST;
static constexpr size_t OFF_CHS    = OFF_BMAX + SZ_BST;
static constexpr size_t OFF_SPIN   = OFF_CHS + SZ_T;
static constexpr size_t SZ_SPIN    = (size_t)NI*2*HW*4;
static constexpr size_t OFF_FLAG   = OFF_SPIN + SZ_SPIN;
static constexpr size_t OFF_WF32   = OFF_FLAG + 256;
// WFT: transposed fusion weights [tap][8192] f32 (294912 B)
static constexpr size_t OFF_WFT    = ((OFF_WF32 + (size_t)W_TOTAL*4 + 255) / 256) * 256;
static constexpr size_t SZ_WFT     = (size_t)9*8192*4;
// P16: slab-planar f16 inputs, [n][slab4][px16384][ech32], 64 MB (optional)
static constexpr size_t OFF_P16    = ((OFF_WFT + SZ_WFT + 255) / 256) * 256;
static constexpr size_t SZ_P16     = (size_t)NI*4*HW*32*2;

// ===========================================================================
// K0: dtype detection (bf16 N(0,1) never has exponent >= 0xC0 in even u16s)
// ===========================================================================
__global__ __launch_bounds__(256) void k0_detect(
    const unsigned short* __restrict__ u, int* __restrict__ flag)
{
  __shared__ int bad;
  if (threadIdx.x == 0) bad = 0;
  __syncthreads();
  int local = 0;
  for (int i = threadIdx.x; i < 4096; i += 256) {
    const unsigned short v = u[2*i];
    const int e = (v >> 7) & 0xFF;
    if (e >= 0xC0) local = 1;
  }
  if (local) atomicOr(&bad, 1);
  __syncthreads();
  if (threadIdx.x == 0) flag[0] = bad;   // 1 => float32 inputs/outputs
}

// ===========================================================================
// KWC: merged weight-convert (+WFT transpose) and P16 pack.  One launch.
// blocks [0,16384): kc_pack body; blocks [16384, 16384+5472): kw body.
// ===========================================================================
struct WPack { const void* p[19]; int sz[19]; int off[19]; };

__global__ __launch_bounds__(256) void kwc_prep(
    WPack wp, const int* __restrict__ flag, float* __restrict__ dst,
    float* __restrict__ WFT,
    const bf16_t* __restrict__ Xb, const bf16_t* __restrict__ Yb,
    const float* __restrict__ Xf, const float* __restrict__ Yf,
    f16_t* __restrict__ P16, const int useP16)
{
  const int b = blockIdx.x;
  const int f32m = flag[0];
  if (b < 16384) {
    if (!useP16) return;
    const int lin = b * 256 + threadIdx.x;            // [0, 4194304)
    const int oct = lin & 3;
    const int p   = (lin >> 2) & 16383;
    const int s   = (lin >> 16) & 3;
    const int n   = lin >> 18;
    const size_t nbase = (size_t)n * CH * HW;
    const int c0 = (s & 1) * 32 + oct * 8;            // channel within X or Y
    const float*  Fsrc = (s < 2) ? Xf : Yf;
    const bf16_t* Bsrc = (s < 2) ? Xb : Yb;
    f16x8 h;
    #pragma unroll
    for (int j = 0; j < 8; ++j) {
      const size_t q = nbase + (size_t)(c0 + j) * HW + p;
      const float v = f32m ? Fsrc[q] : (float)Bsrc[q];
      h[j] = (f16_t)v;
    }
    *(f16x8*)(P16 + (size_t)lin * 8) = h;
  } else {
    const int bb = b - 16384;                         // 0..5471
    const int j  = bb / 288;                          // 0..18
    const int bx = bb % 288;
    const int i = bx * 256 + threadIdx.x;
    if (i >= wp.sz[j]) return;
    float v;
    if (f32m) v = ((const float*)wp.p[j])[i];
    else      v = (float)((const bf16_t*)wp.p[j])[i];
    dst[wp.off[j] + i] = v;
    if (j == 7) WFT[(i % 9) * 8192 + (i / 9)] = v;    // WF -> [tap][o*128+c]
  }
}

// ===========================================================================
// K1: partial Gram per (n, chunk).  grid (NCK=16, 16 n), block 256 (4 waves)
// f32 mode: split-bf16 (hi+lo), 3 MFMAs; D: row=quad*4+reg, col=lane&15
// ===========================================================================
__global__ __launch_bounds__(256) void k1_gram(
    const bf16_t* __restrict__ Xb, const bf16_t* __restrict__ Yb,
    const float* __restrict__ Xf, const float* __restrict__ Yf,
    const int* __restrict__ flag,
    float* __restrict__ Gpart, float* __restrict__ sxpart, float* __restrict__ sypart)
{
  const int chunk = blockIdx.x, n = blockIdx.y;
  const int t = threadIdx.x, lane = t & 63, wv = t >> 6;
  const int mrow = lane & 15, quad = lane >> 4;
  const int f32m = flag[0];
  const size_t nbase = (size_t)n * CH * HW;
  const int p0 = chunk * 1024 + wv * 256;

  f32x4 acc[4][4], acc2[4][4];
  #pragma unroll
  for (int i = 0; i < 4; ++i)
    #pragma unroll
    for (int j = 0; j < 4; ++j) {
      acc[i][j]  = (f32x4){0.f, 0.f, 0.f, 0.f};
      acc2[i][j] = (f32x4){0.f, 0.f, 0.f, 0.f};
    }
  float sxl[4] = {0.f,0.f,0.f,0.f}, syl[4] = {0.f,0.f,0.f,0.f};

  for (int kt = 0; kt < 8; ++kt) {
    const int pk = p0 + kt * 32 + quad * 8;
    if (f32m) {
      bf16x8 a[4], b[4], al[4], bl[4];
      #pragma unroll
      for (int mt = 0; mt < 4; ++mt) {
        const size_t ia = nbase + (size_t)(mt*16 + mrow) * HW + pk;
        float sa = 0.f, sb = 0.f;
        #pragma unroll
        for (int j = 0; j < 8; ++j) {
          const float va = Xf[ia + j];
          const bf16_t ha = (bf16_t)va;
          a[mt][j] = ha; al[mt][j] = (bf16_t)(va - (float)ha); sa += va;
          const float vb = Yf[ia + j];
          const bf16_t hb = (bf16_t)vb;
          b[mt][j] = hb; bl[mt][j] = (bf16_t)(vb - (float)hb); sb += vb;
        }
        sxl[mt] += sa; syl[mt] += sb;
      }
      #pragma unroll
      for (int mt = 0; mt < 4; ++mt)
        #pragma unroll
        for (int nt = 0; nt < 4; ++nt) {
          acc[mt][nt]  = __builtin_amdgcn_mfma_f32_16x16x32_bf16(a[mt],  b[nt],  acc[mt][nt],  0, 0, 0);
          acc2[mt][nt] = __builtin_amdgcn_mfma_f32_16x16x32_bf16(a[mt],  bl[nt], acc2[mt][nt], 0, 0, 0);
          acc2[mt][nt] = __builtin_amdgcn_mfma_f32_16x16x32_bf16(al[mt], b[nt],  acc2[mt][nt], 0, 0, 0);
        }
    } else {
      bf16x8 a[4], b[4];
      #pragma unroll
      for (int mt = 0; mt < 4; ++mt) {
        const size_t ia = nbase + (size_t)(mt*16 + mrow) * HW + pk;
        a[mt] = *(const bf16x8*)(Xb + ia);
        b[mt] = *(const bf16x8*)(Yb + ia);
        float sa = 0.f, sb = 0.f;
        #pragma unroll
        for (int j = 0; j < 8; ++j) { sa += (float)a[mt][j]; sb += (float)b[mt][j]; }
        sxl[mt] += sa; syl[mt] += sb;
      }
      #pragma unroll
      for (int mt = 0; mt < 4; ++mt)
        #pragma unroll
        for (int nt = 0; nt < 4; ++nt)
          acc[mt][nt] = __builtin_amdgcn_mfma_f32_16x16x32_bf16(a[mt], b[nt], acc[mt][nt], 0, 0, 0);
    }
  }

  #pragma unroll
  for (int mt = 0; mt < 4; ++mt) {
    sxl[mt] += __shfl_xor(sxl[mt], 16, 64); sxl[mt] += __shfl_xor(sxl[mt], 32, 64);
    syl[mt] += __shfl_xor(syl[mt], 16, 64); syl[mt] += __shfl_xor(syl[mt], 32, 64);
  }

  __shared__ float Gs[4096];
  __shared__ float sxs[64], sys[64];
  for (int w2 = 0; w2 < 4; ++w2) {
    if (wv == w2) {
      #pragma unroll
      for (int mt = 0; mt < 4; ++mt) {
        #pragma unroll
        for (int nt = 0; nt < 4; ++nt) {
          #pragma unroll
          for (int r = 0; r < 4; ++r) {
            const int c = mt*16 + quad*4 + r, d = nt*16 + mrow;
            const float val = acc[mt][nt][r] + acc2[mt][nt][r];
            if (w2 == 0) Gs[c*64 + d]  = val;
            else         Gs[c*64 + d] += val;
          }
        }
        if (quad == 0) {
          const int c = mt*16 + mrow;
          if (w2 == 0) { sxs[c] = sxl[mt];  sys[c] = syl[mt]; }
          else         { sxs[c] += sxl[mt]; sys[c] += syl[mt]; }
        }
      }
    }
    __syncthreads();
  }
  float* Gp = Gpart + ((size_t)n*NCK + chunk) * 4096;
  for (int i = t; i < 4096; i += 256) Gp[i] = Gs[i];
  if (t < 64)       sxpart[((size_t)n*NCK + chunk)*64 + t]        = sxs[t];
  else if (t < 128) sypart[((size_t)n*NCK + chunk)*64 + (t - 64)] = sys[t - 64];
}

// ===========================================================================
// K2a: attention small math.  grid (4, NI) -- blockIdx.x = half*2+dir.
// (R12, unchanged)
// ===========================================================================
__global__ __launch_bounds__(256, 1) void k2a_attn(
    const float* __restrict__ Gpart, const float* __restrict__ sxpart, const float* __restrict__ sypart,
    const float* __restrict__ wt,
    float* __restrict__ M1, float* __restrict__ M2,
    float* __restrict__ T1, float* __restrict__ T2)
{
  const int bx = blockIdx.x, n = blockIdx.y;
  const int dir  = bx & 1;          // 0: s1 path, 1: s2 path
  const int c0   = (bx >> 1) * 32;  // c-half base
  const int t = threadIdx.x;
  constexpr int SW = 68;            // 272 B rows: 16B-aligned for all rows
  __shared__ float Gs[4096];
  __shared__ float Ps[4096];        // P rows (own c half used)
  __shared__ float As[64*SW];       // A rows (own c half used)
  __shared__ float WQs[64*SW], WKs[64*SW], WVs[64*SW];
  __shared__ float sxs[64], sys[64], uu[64], vv[64];

  for (int i = t; i < 4096; i += 256) {
    const int r = i >> 6, cc = i & 63;
    WQs[r*SW + cc] = wt[W_WQ + i];
    WKs[r*SW + cc] = wt[W_WK + i];
    WVs[r*SW + cc] = wt[W_WV + i];
  }
  for (int i4 = t; i4 < 1024; i4 += 256) {
    f32x4 s = (f32x4){0.f, 0.f, 0.f, 0.f};
    for (int c2 = 0; c2 < NCK; ++c2)
      s += *(const f32x4*)(Gpart + ((size_t)n*NCK + c2)*4096 + i4*4);
    *(f32x4*)(Gs + i4*4) = s;
  }
  if (t < 64) {
    float s = 0.f; for (int c2 = 0; c2 < NCK; ++c2) s += sxpart[((size_t)n*NCK + c2)*64 + t];
    sxs[t] = s;
  } else if (t < 128) {
    const int c = t - 64;
    float s = 0.f; for (int c2 = 0; c2 < NCK; ++c2) s += sypart[((size_t)n*NCK + c2)*64 + c];
    sys[c] = s;
  }
  __syncthreads();

  // ---- phase 2: P = WQ·G (dir0) or WQ·Gᵀ (dir1), own c rows ----
  {
    const int e = t & 63;
    float Greg[64];
    if (dir == 0) {
      #pragma unroll
      for (int a = 0; a < 64; ++a) Greg[a] = Gs[a*64 + e];     // col e
    } else {
      #pragma unroll
      for (int a4 = 0; a4 < 16; ++a4)                          // row e
        *(f32x4*)(Greg + a4*4) = *(const f32x4*)(Gs + e*64 + a4*4);
    }
    for (int it = 0; it < 8; ++it) {
      const int c = c0 + (t >> 6) + 4*it;                      // wave-uniform
      float s1 = 0.f;
      #pragma unroll
      for (int a4 = 0; a4 < 16; ++a4) {
        const f32x4 w4 = *(const f32x4*)(WQs + c*SW + a4*4);   // uniform b128
        #pragma unroll
        for (int r = 0; r < 4; ++r) s1 += w4[r] * Greg[a4*4 + r];
      }
      Ps[c*64 + e] = s1;
    }
  }
  // ---- uu[all c], vv[all d] ----
  {
    const int c = t & 63;
    if (t < 64) {
      const float* vecv = dir ? sys : sxs;
      float s = 0.f;
      #pragma unroll
      for (int a = 0; a < 64; ++a) s += WQs[c*SW + a] * vecv[a];
      uu[c] = s;
    } else if (t < 128) {
      const float* vecv = dir ? sxs : sys;
      float s = 0.f;
      #pragma unroll
      for (int a = 0; a < 64; ++a) s += WKs[c*SW + a] * vecv[a];
      vv[c] = s;
    }
  }
  __syncthreads();

  // ---- phase 3: A = P·WKᵀ + bias, own c rows ----
  {
    const int d = t & 63;
    float WKreg[64];
    #pragma unroll
    for (int a4 = 0; a4 < 16; ++a4)
      *(f32x4*)(WKreg + a4*4) = *(const f32x4*)(WKs + d*SW + a4*4);
    const float bkd = wt[W_BK + d];
    for (int it = 0; it < 8; ++it) {
      const int c = c0 + (t >> 6) + 4*it;
      float s1 = 0.f;
      #pragma unroll
      for (int e4 = 0; e4 < 16; ++e4) {
        const f32x4 p1 = *(const f32x4*)(Ps + c*64 + e4*4);    // uniform b128
        #pragma unroll
        for (int r = 0; r < 4; ++r) s1 += p1[r] * WKreg[e4*4 + r];
      }
      const float bqc = wt[W_BQ + c];
      s1 += uu[c]*bkd + bqc*vv[d] + 16384.f*bqc*bkd;
      As[c*SW + d] = s1;
    }
  }
  __syncthreads();

  // ---- softmax rows (own 32 rows) ----
  if (t < 32) {
    float* R = As + (c0 + t)*SW;
    float m = R[0];
    for (int d = 1; d < 64; ++d) m = fmaxf(m, R[d]);
    float s = 0.f;
    for (int d = 0; d < 64; ++d) { const float e2 = expf(R[d] - m); R[d] = e2; s += e2; }
    const float inv = 1.f / s;
    for (int d = 0; d < 64; ++d) R[d] *= inv;
  }
  __syncthreads();

  // ---- phase 5: M = A·WV, own c rows (+T tail) ----
  {
    const int e = t & 63;
    float WVreg[64];
    #pragma unroll
    for (int dd = 0; dd < 64; ++dd) WVreg[dd] = WVs[dd*SW + e];
    float* Mo = (dir ? M2 : M1) + (size_t)n*4096;
    for (int it = 0; it < 8; ++it) {
      const int c = c0 + (t >> 6) + 4*it;
      float s1 = 0.f;
      #pragma unroll
      for (int d4 = 0; d4 < 16; ++d4) {
        const f32x4 a1 = *(const f32x4*)(As + c*SW + d4*4);    // uniform b128
        #pragma unroll
        for (int r = 0; r < 4; ++r) s1 += a1[r] * WVreg[d4*4 + r];
      }
      Mo[c*64 + e] = s1;
    }
  }
  if (t < 32) {
    const int c = c0 + t;
    float s1 = 0.f;
    for (int d = 0; d < 64; ++d) s1 += As[c*SW + d] * wt[W_BV + d];
    (dir ? T2 : T1)[n*64 + c] = s1;
  }
}

// ===========================================================================
// K2b: effective conv weights -> fp16 Wh[n][o][tap][128] (+windT, bconst).
// grid (9 taps, 2 dirs, 16 n), block 256.  (R10, unchanged)
// ===========================================================================
__global__ __launch_bounds__(256) void k2b_weff(
    const float* __restrict__ wt, const float* __restrict__ WFT,
    const float* __restrict__ M1, const float* __restrict__ M2,
    const float* __restrict__ T1, const float* __restrict__ T2,
    f16_t* __restrict__ Wh, float* __restrict__ windT, float* __restrict__ bconst)
{
  const int tap = blockIdx.x, dir = blockIdx.y, n = blockIdx.z;
  const int t = threadIdx.x;
  const float g = wt[W_GAMMA];
  f16_t* Whn = Wh + (size_t)n * 64 * 9 * 128;
  const float* Mo = (dir == 0) ? (M2 + (size_t)n*4096) : (M1 + (size_t)n*4096);

  __shared__ float Wfs[8192];   // [o][0..127] WF row slice at this tap
  __shared__ float Ms[4096];    // Mo[c][e]

  for (int i4 = t; i4 < 2048; i4 += 256)
    *(f32x4*)(Wfs + i4*4) = *(const f32x4*)(WFT + (size_t)tap*8192 + i4*4);
  for (int i4 = t; i4 < 1024; i4 += 256)
    *(f32x4*)(Ms + i4*4) = *(const f32x4*)(Mo + i4*4);
  __syncthreads();

  const int e = t & 63;
  float Msreg[64];
  #pragma unroll
  for (int c = 0; c < 64; ++c) Msreg[c] = Ms[c*64 + e];
  const int coff = dir ? 0 : 64;        // inner-sum weight half
  const int boff = dir ? 64 : 0;        // base half
  for (int it = 0; it < 16; ++it) {
    const int o = (t >> 6) + 4*it;      // wave-uniform
    const float inv = wt[W_BNG + o] * rsqrtf(wt[W_BNV + o] + 1e-5f);
    const float base = Wfs[o*128 + boff + e];
    float s = 0.f;
    #pragma unroll
    for (int c4 = 0; c4 < 16; ++c4) {
      const f32x4 w4 = *(const f32x4*)(Wfs + o*128 + coff + c4*4);
      #pragma unroll
      for (int r = 0; r < 4; ++r) s += w4[r] * Msreg[c4*4 + r];
    }
    Whn[(o*9 + tap)*128 + dir*64 + e] = (f16_t)(inv * (base + g * s));
  }

  if (dir == 0 && t < 64) {
    const int o = t;
    const float inv = wt[W_BNG + o] * rsqrtf(wt[W_BNV + o] + 1e-5f);
    float s = 0.f;
    for (int c = 0; c < 64; ++c)
      s += wt[W_WF + (o*128 + c)*9 + tap]      * T1[n*64 + c]
         + wt[W_WF + (o*128 + 64 + c)*9 + tap] * T2[n*64 + c];
    windT[((size_t)n*9 + tap)*64 + o] = inv * g * s;
    if (tap == 0 && n == 0)
      bconst[o] = wt[W_BF + o]*inv + wt[W_BNB + o] - wt[W_BNM + o]*inv;
  }
}

// ===========================================================================
// K3: implicit-GEMM conv via MFMA f16.
// grid (32 row-quads, 16 n), block 512 (8 waves); sbuf DOUBLE-buffered
// 2x[6][130][40] (125 KB): write slab s+1 into buf[(s+1)&1] AFTER compute
// with no second barrier -- next iteration's single barrier is the
// write/read rendezvous.  Safety: a wave writing buf b at end of iter s has
// passed barrier(s), which all waves reach only after finishing their iter
// s-1 compute (the last readers of b).  One barrier per slab.  Border table
// from windT in-prologue.  (R15, measured best)
// ===========================================================================
__global__ __launch_bounds__(512) void k3_conv(
    const bf16_t* __restrict__ Xb, const bf16_t* __restrict__ Yb,
    const float* __restrict__ Xf, const float* __restrict__ Yf,
    const int* __restrict__ flag,
    const f16_t* __restrict__ Wh, const float* __restrict__ bconst,
    const float* __restrict__ windT,
    const f16_t* __restrict__ P16, const int useP16,
    bf16_t* __restrict__ fusedB, float* __restrict__ fusedF,
    float* __restrict__ bsum, float* __restrict__ bmax)
{
  __shared__ __attribute__((aligned(16))) f16_t sbuf[2][6][130][40];
  __shared__ float sind[576], sconst[64];
  __shared__ float ssum[8][64], smax[8][64];
  const int rp = blockIdx.x, n = blockIdx.y;        // rp: 0..31 (4 rows each)
  const int t = threadIdx.x, lane = t & 63, wv = t >> 6;
  const int l15 = lane & 15, quad = lane >> 4;
  const int ly = wv >> 1, ch2 = wv & 1;
  const int f32m = flag[0];
  const size_t nbase = (size_t)n * CH * HW;
  const f16_t* __restrict__ Whn = Wh + (size_t)n * 64 * 9 * 128;

  // border table from windT (k2c folded in)
  for (int i = t; i < 576; i += 512) {
    const int g = i >> 6, o = i & 63;
    const int yc = g / 3, xc = g % 3;
    const int ky0 = (yc == 0) ? 1 : 0, ky1 = (yc == 2) ? 1 : 2;
    const int kx0 = (xc == 0) ? 1 : 0, kx1 = (xc == 2) ? 1 : 2;
    float sv = 0.f;
    for (int ky = ky0; ky <= ky1; ++ky)
      for (int kx = kx0; kx <= kx1; ++kx)
        sv += windT[((size_t)n*9 + ky*3 + kx)*64 + o];
    sind[i] = sv;
  }
  if (t < 64) sconst[t] = bconst[t];
  for (int i = t; i < 768; i += 512) {  // zero halo cols, both buffers
    const int bq = (i >= 384) ? 1 : 0;
    const int ii = i - bq*384;
    const int r = ii >> 6, cs = (ii >> 5) & 1, sl = ii & 31;
    sbuf[bq][r][cs ? 129 : 0][sl] = (f16_t)0.f;
  }

  f32x4 acc[4][4];
  #pragma unroll
  for (int i = 0; i < 4; ++i)
    #pragma unroll
    for (int j = 0; j < 4; ++j) acc[i][j] = (f32x4){0.f, 0.f, 0.f, 0.f};

  if (useP16) {
    const int oct = t & 3;
    const int x   = t >> 2;                 // 0..127
    const f16_t* __restrict__ PnB = P16 + (size_t)(n*4) * HW * 32;
    f16x8 h[6];

    #define K3_STAGE_LOAD(S)                                                  \
      { const f16_t* __restrict__ Pn = PnB + (size_t)(S) * HW * 32;           \
        _Pragma("unroll")                                                     \
        for (int i = 0; i < 6; ++i) {                                         \
          const int gy = rp*4 - 1 + i;                                        \
          f16x8 v;                                                            \
          _Pragma("unroll")                                                   \
          for (int k2 = 0; k2 < 8; ++k2) v[k2] = (f16_t)0.f;                  \
          if (gy >= 0 && gy < H)                                              \
            v = *(const f16x8*)(Pn + ((size_t)(gy*128 + x) * 32 + oct*8));    \
          h[i] = v;                                                           \
        } }
    #define K3_STAGE_WRITE(B)                                                 \
      { const int colL = x + 1;                                               \
        _Pragma("unroll")                                                     \
        for (int i = 0; i < 6; ++i)                                           \
          *(f16x8*)&sbuf[B][i][colL][(oct ^ (colL & 3)) * 8] = h[i];          \
      }

    K3_STAGE_LOAD(0)
    K3_STAGE_WRITE(0)
    for (int s = 0; s < 4; ++s) {
      const int cur = s & 1;
      if (s < 3) K3_STAGE_LOAD(s + 1)       // in flight across the barrier
      asm volatile("s_waitcnt lgkmcnt(0)" ::: "memory");
      __builtin_amdgcn_s_barrier();         // writes to buf[cur] visible
      __builtin_amdgcn_s_setprio(1);
      #pragma unroll
      for (int tap = 0; tap < 9; ++tap) {
        const int ky = tap / 3, kx = tap % 3;
        f16x8 bfr[4];
        #pragma unroll
        for (int nt = 0; nt < 4; ++nt) {
          const int o = nt*16 + l15;
          bfr[nt] = *(const f16x8*)(Whn + ((o*9 + tap)*128 + s*32 + quad*8));
        }
        f16x8 afr[4];
        const int row = ly + ky;
        #pragma unroll
        for (int mt = 0; mt < 4; ++mt) {
          const int col = ch2*64 + mt*16 + l15 + kx;
          afr[mt] = *(const f16x8*)&sbuf[cur][row][col][(quad ^ (col & 3)) * 8];
        }
        #pragma unroll
        for (int mt = 0; mt < 4; ++mt)
          #pragma unroll
          for (int nt = 0; nt < 4; ++nt)
            acc[mt][nt] = __builtin_amdgcn_mfma_f32_16x16x32_f16(afr[mt], bfr[nt], acc[mt][nt], 0, 0, 0);
      }
      __builtin_amdgcn_s_setprio(0);
      if (s < 3) K3_STAGE_WRITE(cur ^ 1)    // no barrier: next iter's barrier
    }                                       // is the write/read rendezvous
    #undef K3_STAGE_LOAD
    #undef K3_STAGE_WRITE
  } else {
    // fallback: classic staged loop, direct global loads + converts
    const int cstage = t & 127, rsel = t >> 7;          // rsel 0..3
    for (int s = 0; s < 4; ++s) {
      __syncthreads();
      #pragma unroll
      for (int pass = 0; pass < 2; ++pass) {
        const int r = rsel + 4*pass;                    // 0..7
        if (r < 6) {
          const int gy = rp*4 - 1 + r;
          const bool valid = (gy >= 0) && (gy < H);
          const int colL = cstage + 1;
          #pragma unroll
          for (int oct = 0; oct < 4; ++oct) {
            f16x8 hh;
            #pragma unroll
            for (int j = 0; j < 8; ++j) {
              const int g = s*32 + oct*8 + j;
              float v = 0.f;
              if (valid) {
                const size_t q = nbase + (size_t)(g & 63)*HW + gy*W + cstage;
                v = (g < 64) ? (f32m ? Xf[q] : (float)Xb[q])
                             : (f32m ? Yf[q] : (float)Yb[q]);
              }
              hh[j] = (f16_t)v;
            }
            *(f16x8*)&sbuf[0][r][colL][(oct ^ (colL & 3)) * 8] = hh;
          }
        }
      }
      __syncthreads();
      #pragma unroll
      for (int tap = 0; tap < 9; ++tap) {
        const int ky = tap / 3, kx = tap % 3;
        f16x8 bfr[4];
        #pragma unroll
        for (int nt = 0; nt < 4; ++nt) {
          const int o = nt*16 + l15;
          bfr[nt] = *(const f16x8*)(Whn + ((o*9 + tap)*128 + s*32 + quad*8));
        }
        f16x8 afr[4];
        const int row = ly + ky;
        #pragma unroll
        for (int mt = 0; mt < 4; ++mt) {
          const int col = ch2*64 + mt*16 + l15 + kx;
          afr[mt] = *(const f16x8*)&sbuf[0][row][col][(quad ^ (col & 3)) * 8];
        }
        #pragma unroll
        for (int mt = 0; mt < 4; ++mt)
          #pragma unroll
          for (int nt = 0; nt < 4; ++nt)
            acc[mt][nt] = __builtin_amdgcn_mfma_f32_16x16x32_f16(afr[mt], bfr[nt], acc[mt][nt], 0, 0, 0);
      }
    }
  }

  // ---- epilogue: + bconst + border const, ReLU, store, channel stats ----
  const int y = rp*4 + ly;
  const int yc = (y == 0) ? 0 : (y == H-1) ? 2 : 1;
  #pragma unroll
  for (int nt = 0; nt < 4; ++nt) {
    const int o = nt*16 + l15;
    const float bc = sconst[o];
    float ssm = 0.f, smx = 0.f;
    #pragma unroll
    for (int mt = 0; mt < 4; ++mt) {
      const int xb = ch2*64 + mt*16 + quad*4;
      f32x4 vals;
      #pragma unroll
      for (int r = 0; r < 4; ++r) {
        const int x = xb + r;
        const int xc = (x == 0) ? 0 : (x == W-1) ? 2 : 1;
        float v = acc[mt][nt][r] + bc + sind[(yc*3 + xc)*64 + o];
        v = fmaxf(v, 0.f);
        vals[r] = v; ssm += v; smx = fmaxf(smx, v);
      }
      const size_t off = nbase + (size_t)o*HW + y*W + xb;
      if (f32m) {
        *(f32x4*)(fusedF + off) = vals;
      } else {
        bf16x4 pv;
        #pragma unroll
        for (int r = 0; r < 4; ++r) pv[r] = (bf16_t)vals[r];
        *(bf16x4*)(fusedB + off) = pv;
      }
    }
    ssm += __shfl_xor(ssm, 16, 64); ssm += __shfl_xor(ssm, 32, 64);
    smx = fmaxf(smx, __shfl_xor(smx, 16, 64));
    smx = fmaxf(smx, __shfl_xor(smx, 32, 64));
    if (quad == 0) { ssum[wv][o] = ssm; smax[wv][o] = smx; }
  }
  __syncthreads();
  if (t < 64) {
    float S = 0.f, M = 0.f;
    #pragma unroll
    for (int w2 = 0; w2 < 8; ++w2) {
      S += ssum[w2][t];
      M = fmaxf(M, smax[w2][t]);
    }
    bsum[((size_t)n*32 + rp)*64 + t] = S;
    bmax[((size_t)n*32 + rp)*64 + t] = M;
  }
}

// ===========================================================================
// K4: CBAM channel gate.  grid 16 (per n), block 256 (4-way rp split).
// ===========================================================================
__global__ __launch_bounds__(256) void k4_chgate(
    const float* __restrict__ bsum, const float* __restrict__ bmax,
    const float* __restrict__ wt, float* __restrict__ chout)
{
  const int n = blockIdx.x, t = threadIdx.x;
  const int o = t & 63, part = t >> 6;
  __shared__ float ps[4][64], pm[4][64];
  __shared__ float avg[64], mxs[64], h1[8], h2[8];
  float S = 0.f, M = 0.f;
  for (int rp = part*8; rp < part*8 + 8; ++rp) {
    S += bsum[((size_t)n*32 + rp)*64 + o];
    M = fmaxf(M, bmax[((size_t)n*32 + rp)*64 + o]);
  }
  ps[part][o] = S; pm[part][o] = M;
  __syncthreads();
  if (t < 64) {
    const float Sa = ((ps[0][t] + ps[1][t]) + ps[2][t]) + ps[3][t];
    const float Ma = fmaxf(fmaxf(pm[0][t], pm[1][t]), fmaxf(pm[2][t], pm[3][t]));
    avg[t] = Sa * (1.f / 16384.f);
    mxs[t] = Ma;
  }
  __syncthreads();
  if (t < 8) {
    float s = wt[W_FC1B + t];
    for (int c = 0; c < 64; ++c) s += wt[W_FC1W + t*64 + c] * avg[c];
    h1[t] = fmaxf(s, 0.f);
  } else if (t < 16) {
    const int r = t - 8;
    float s = wt[W_FC1B + r];
    for (int c = 0; c < 64; ++c) s += wt[W_FC1W + r*64 + c] * mxs[c];
    h2[r] = fmaxf(s, 0.f);
  }
  __syncthreads();
  if (t < 64) {
    float s = 2.f * wt[W_FC2B + t];
    for (int r = 0; r < 8; ++r) s += wt[W_FC2W + t*8 + r] * (h1[r] + h2[r]);
    chout[n*64 + t] = 1.f / (1.f + expf(-s));
  }
}

// ===========================================================================
// K5: spatial-attention inputs (per-pixel channel mean/max of fused*ch).
// grid (32, NI), block 256 (4 waves).  (R14, unchanged)
// ===========================================================================
__global__ __launch_bounds__(256) void k5_spin(
    const bf16_t* __restrict__ fusedB, const float* __restrict__ fusedF,
    const int* __restrict__ flag,
    const float* __restrict__ chs, float* __restrict__ spin)
{
  const int n = blockIdx.y;
  const int t = threadIdx.x, w = t >> 6, lane = t & 63;
  const int px0 = blockIdx.x * 512 + lane * 8;
  const int f32m = flag[0];
  const size_t nbase = (size_t)n * CH * HW;
  const float* c = chs + n * 64;
  __shared__ float Ssum[4][64][9], Smax[4][64][9];   // pad 9: conflict-free
  float s[8], m[8];
  #pragma unroll
  for (int k = 0; k < 8; ++k) { s[k] = 0.f; m[k] = 0.f; }
  const int o0 = w * 16;
  if (f32m) {
    for (int oi = 0; oi < 16; ++oi) {
      const int o = o0 + oi;
      const float co = c[o];
      const float* q = fusedF + nbase + (size_t)o*HW + px0;
      const f32x4 a = *(const f32x4*)q;
      const f32x4 b = *(const f32x4*)(q + 4);
      #pragma unroll
      for (int k = 0; k < 4; ++k) {
        const float v0 = a[k] * co; s[k]   += v0; m[k]   = fmaxf(m[k],   v0);
        const float v1 = b[k] * co; s[4+k] += v1; m[4+k] = fmaxf(m[4+k], v1);
      }
    }
  } else {
    for (int oi = 0; oi < 16; ++oi) {
      const int o = o0 + oi;
      const float co = c[o];
      const bf16x8 a = *(const bf16x8*)(fusedB + nbase + (size_t)o*HW + px0);
      #pragma unroll
      for (int k = 0; k < 8; ++k) {
        const float v = (float)a[k] * co; s[k] += v; m[k] = fmaxf(m[k], v);
      }
    }
  }
  #pragma unroll
  for (int k = 0; k < 8; ++k) { Ssum[w][lane][k] = s[k]; Smax[w][lane][k] = m[k]; }
  __syncthreads();
  if (t < 64) {
    const int p0 = blockIdx.x * 512 + t * 8;
    f32x4 o0v, o1v, o2v, o3v;
    #pragma unroll
    for (int k = 0; k < 8; ++k) {
      const float S = ((Ssum[0][t][k] + Ssum[1][t][k]) + Ssum[2][t][k]) + Ssum[3][t][k];
      const float M = fmaxf(fmaxf(Smax[0][t][k], Smax[1][t][k]),
                            fmaxf(Smax[2][t][k], Smax[3][t][k]));
      if (k < 4) { o0v[k] = S * (1.f/64.f); o2v[k] = M; }
      else       { o1v[k-4] = S * (1.f/64.f); o3v[k-4] = M; }
    }
    *(f32x4*)(spin + (size_t)n*2*HW + p0)          = o0v;
    *(f32x4*)(spin + (size_t)n*2*HW + p0 + 4)      = o1v;
    *(f32x4*)(spin + (size_t)n*2*HW + HW + p0)     = o2v;
    *(f32x4*)(spin + (size_t)n*2*HW + HW + p0 + 4) = o3v;
  }
}

// ===========================================================================
// K6: 7x7 spatial conv + sigmoid + final scale (in-place on d_out).
// grid (32, NI), block 256.  (R14, unchanged)
// ===========================================================================
__global__ __launch_bounds__(256) void k6_final(
    bf16_t* __restrict__ fusedB, float* __restrict__ fusedF,
    const int* __restrict__ flag,
    const float* __restrict__ chs, const float* __restrict__ spin,
    const float* __restrict__ wt)
{
  const int n = blockIdx.y;
  const int t = threadIdx.x;
  const int y0 = blockIdx.x * 4;
  const int f32m = flag[0];
  const float* s0 = spin + (size_t)n*2*HW;
  const float* s1 = s0 + HW;
  __shared__ float s0l[10][128], s1l[10][128];
  __shared__ float spl[8][64];                 // [pxk][pxgroup] transposed

  for (int i = t; i < 1280; i += 256) {
    const int r = i >> 7, x = i & 127;
    const int yy = y0 - 3 + r;
    const bool ok = (yy >= 0) && (yy < H);
    s0l[r][x] = ok ? s0[yy*W + x] : 0.f;
    s1l[r][x] = ok ? s1[yy*W + x] : 0.f;
  }
  __syncthreads();

  #pragma unroll
  for (int pp = 0; pp < 2; ++pp) {
    const int pl = t*2 + pp;                   // 0..511
    const int ly = pl >> 7, x = pl & 127;
    float acc = wt[W_SAB];
    #pragma unroll
    for (int j = 0; j < 7; ++j) {
      const int row = ly + j;                  // LDS row for yy = y0+ly+j-3
      #pragma unroll
      for (int i = 0; i < 7; ++i) {
        const int xx = x + i - 3;
        const bool ok = (xx >= 0) && (xx < W);
        const float v0 = ok ? s0l[row][xx] : 0.f;
        const float v1 = ok ? s1l[row][xx] : 0.f;
        acc += wt[W_SAW + j*7 + i] * v0 + wt[W_SAW + 49 + j*7 + i] * v1;
      }
    }
    spl[pl & 7][pl >> 3] = 1.f / (1.f + expf(-acc));
  }
  __syncthreads();

  const size_t nbase = (size_t)n * CH * HW;
  const float* c = chs + n * 64;
  const int g = t & 63;                        // px group (8 px)
  const int p0 = y0*W + g*8;
  float sp[8];
  #pragma unroll
  for (int k = 0; k < 8; ++k) sp[k] = spl[k][g];
  for (int it = 0; it < 16; ++it) {
    const int o = it*4 + (t >> 6);             // wave-uniform channel
    const float co = c[o];
    if (f32m) {
      float* q = fusedF + nbase + (size_t)o*HW + p0;
      f32x4 a = *(f32x4*)q;
      f32x4 b = *(f32x4*)(q + 4);
      #pragma unroll
      for (int k = 0; k < 4; ++k) {
        a[k] = a[k] * co * sp[k];
        b[k] = b[k] * co * sp[4+k];
      }
      *(f32x4*)q       = a;
      *(f32x4*)(q + 4) = b;
    } else {
      bf16_t* q = fusedB + nbase + (size_t)o*HW + p0;
      bf16x8 a = *(bf16x8*)q;
      #pragma unroll
      for (int k = 0; k < 8; ++k)
        a[k] = (bf16_t)((float)a[k] * co * sp[k]);
      *(bf16x8*)q = a;
    }
  }
}

// ===========================================================================
extern "C" void kernel_launch(void* const* d_in, const int* in_sizes, int n_in,
                              void* d_out, int out_size, void* d_ws, size_t ws_size,
                              hipStream_t stream)
{
  (void)n_in; (void)out_size; (void)in_sizes;
  char* ws = (char*)d_ws;
  float*  Gpart  = (float*)(ws + OFF_GPART);
  float*  sxp    = (float*)(ws + OFF_SX);
  float*  syp    = (float*)(ws + OFF_SY);
  float*  M1     = (float*)(ws + OFF_M1);
  float*  M2     = (float*)(ws + OFF_M2);
  float*  T1     = (float*)(ws + OFF_T1);
  float*  T2     = (float*)(ws + OFF_T2);
  float*  bconst = (float*)(ws + OFF_BCONST);
  f16_t*  Wh     = (f16_t*)(ws + OFF_WH);
  float*  windT  = (float*)(ws + OFF_WINDT);
  float*  bsum   = (float*)(ws + OFF_BSUM);
  float*  bmax   = (float*)(ws + OFF_BMAX);
  float*  chs    = (float*)(ws + OFF_CHS);
  float*  spin   = (float*)(ws + OFF_SPIN);
  int*    flag   = (int*)  (ws + OFF_FLAG);
  float*  wf32   = (float*)(ws + OFF_WF32);
  float*  wft    = (float*)(ws + OFF_WFT);
  f16_t*  P16    = (f16_t*)(ws + OFF_P16);
  bf16_t* fusedB = (bf16_t*)d_out;
  float*  fusedF = (float*)d_out;

  const int useP16 = (ws_size >= OFF_P16 + SZ_P16) ? 1 : 0;

  const bf16_t* imgB = (const bf16_t*)d_in[0];
  const bf16_t* depB = (const bf16_t*)d_in[1];
  const float*  imgF = (const float*) d_in[0];
  const float*  depF = (const float*) d_in[1];

  WPack wp;
  static const int wsz[19] = {4096,64,4096,64,4096,64,1,73728,64,64,64,64,64,512,8,512,64,98,1};
  static const int woff[19] = {W_WQ,W_BQ,W_WK,W_BK,W_WV,W_BV,W_GAMMA,W_WF,W_BF,W_BNG,
                               W_BNB,W_BNM,W_BNV,W_FC1W,W_FC1B,W_FC2W,W_FC2B,W_SAW,W_SAB};
  for (int j = 0; j < 19; ++j) { wp.p[j] = d_in[2 + j]; wp.sz[j] = wsz[j]; wp.off[j] = woff[j]; }

  hipLaunchKernelGGL(k0_detect, dim3(1), dim3(256), 0, stream,
                     (const unsigned short*)d_in[0], flag);
  hipLaunchKernelGGL(kwc_prep, dim3(16384 + 5472), dim3(256), 0, stream,
                     wp, flag, wf32, wft, imgB, depB, imgF, depF, P16, useP16);
  hipLaunchKernelGGL(k1_gram,  dim3(NCK, NI), dim3(256), 0, stream,
                     imgB, depB, imgF, depF, flag, Gpart, sxp, syp);
  hipLaunchKernelGGL(k2a_attn, dim3(4, NI), dim3(256), 0, stream,
                     Gpart, sxp, syp, wf32, M1, M2, T1, T2);
  hipLaunchKernelGGL(k2b_weff, dim3(9, 2, NI), dim3(256), 0, stream,
                     wf32, wft, M1, M2, T1, T2, Wh, windT, bconst);
  hipLaunchKernelGGL(k3_conv,  dim3(32, NI), dim3(512), 0, stream,
                     imgB, depB, imgF, depF, flag, Wh, bconst, windT,
                     P16, useP16, fusedB, fusedF, bsum, bmax);
  hipLaunchKernelGGL(k4_chgate, dim3(NI), dim3(256), 0, stream,
                     bsum, bmax, wf32, chs);
  hipLaunchKernelGGL(k5_spin,  dim3(32, NI), dim3(256), 0, stream,
                     fusedB, fusedF, flag, chs, spin);
  hipLaunchKernelGGL(k6_final, dim3(32, NI), dim3(256), 0, stream,
                     fusedB, fusedF, flag, chs, spin, wf32);
}